// Round 1
// baseline (381.238 us; speedup 1.0000x reference)
//
#include <hip/hip_runtime.h>
#include <math.h>

#define L_SAMP 128
#define N_TOT  65536
#define DIM    8
#define DZ_DIM 16
#define NTRI   (DIM*(DIM+1)/2)   // 36

// One thread per n. Streams y_pred_array[l][n][0..7] over l, accumulates
// sums + upper-triangular product sums, then does an 8x8 Cholesky for
// logdet + quadratic form, plus the KL term. Wave-reduces in double and
// atomically accumulates into ws[0]=sum_kl, ws[1]=sum_rec.
__global__ __launch_bounds__(256, 1) void loss_main_kernel(
    const float* __restrict__ y_true,
    const float* __restrict__ y_pred,
    const float* __restrict__ mu,
    const float* __restrict__ Sigma,
    double* __restrict__ ws_acc)
{
    const int n = blockIdx.x * blockDim.x + threadIdx.x;

    float s[DIM];
    float p[NTRI];
#pragma unroll
    for (int d = 0; d < DIM; ++d) s[d] = 0.0f;
#pragma unroll
    for (int i = 0; i < NTRI; ++i) p[i] = 0.0f;

    const float4* base = reinterpret_cast<const float4*>(y_pred + (size_t)n * DIM);
    const size_t strideF4 = (size_t)N_TOT * DIM / 4;   // float4 units per l-step

#pragma unroll 4
    for (int l = 0; l < L_SAMP; ++l) {
        float4 a = base[(size_t)l * strideF4];
        float4 b = base[(size_t)l * strideF4 + 1];
        float y[DIM] = {a.x, a.y, a.z, a.w, b.x, b.y, b.z, b.w};
#pragma unroll
        for (int d = 0; d < DIM; ++d) s[d] += y[d];
        int idx = 0;
#pragma unroll
        for (int d = 0; d < DIM; ++d) {
#pragma unroll
            for (int e = d; e < DIM; ++e) {
                p[idx] += y[d] * y[e];
                ++idx;
            }
        }
    }

    // mean and covariance:  C = (P - L*mean*mean^T) / (L-1)
    float mean[DIM];
#pragma unroll
    for (int d = 0; d < DIM; ++d) mean[d] = s[d] * (1.0f / L_SAMP);

    float C[DIM][DIM];
    {
        int idx = 0;
#pragma unroll
        for (int d = 0; d < DIM; ++d) {
#pragma unroll
            for (int e = d; e < DIM; ++e) {
                float c = (p[idx] - (float)L_SAMP * mean[d] * mean[e]) * (1.0f / (L_SAMP - 1));
                C[d][e] = c;
                C[e][d] = c;
                ++idx;
            }
        }
    }

    // m = mean - y_true[n]
    const float4* yt = reinterpret_cast<const float4*>(y_true + (size_t)n * DIM);
    float4 t0 = yt[0];
    float4 t1 = yt[1];
    float m[DIM] = {mean[0] - t0.x, mean[1] - t0.y, mean[2] - t0.z, mean[3] - t0.w,
                    mean[4] - t1.x, mean[5] - t1.y, mean[6] - t1.z, mean[7] - t1.w};

    // Cholesky C = G G^T (lower). logdet(C) = sum log(diag residual).
    float G[DIM][DIM];
    float logdet = 0.0f;
#pragma unroll
    for (int k = 0; k < DIM; ++k) {
        float diag = C[k][k];
#pragma unroll
        for (int j = 0; j < DIM; ++j) {
            if (j < k) diag -= G[k][j] * G[k][j];
        }
        float gkk = sqrtf(diag);
        G[k][k] = gkk;
        logdet += logf(diag);
        float inv = 1.0f / gkk;
#pragma unroll
        for (int i = 0; i < DIM; ++i) {
            if (i > k) {
                float v = C[i][k];
#pragma unroll
                for (int j = 0; j < DIM; ++j) {
                    if (j < k) v -= G[i][j] * G[k][j];
                }
                G[i][k] = v * inv;
            }
        }
    }

    // Forward solve G z = m; quad = m^T C^-1 m = ||z||^2
    float z[DIM];
    float quad = 0.0f;
#pragma unroll
    for (int i = 0; i < DIM; ++i) {
        float v = m[i];
#pragma unroll
        for (int j = 0; j < DIM; ++j) {
            if (j < i) v -= G[i][j] * z[j];
        }
        z[i] = v / G[i][i];
        quad += z[i] * z[i];
    }
    float rec = 0.5f * (logdet + quad);

    // KL term: 0.5 * sum_j (mu^2 + Sigma - log Sigma - 1)
    const float4* muv = reinterpret_cast<const float4*>(mu + (size_t)n * DZ_DIM);
    const float4* sgv = reinterpret_cast<const float4*>(Sigma + (size_t)n * DZ_DIM);
    float kl = 0.0f;
#pragma unroll
    for (int j = 0; j < DZ_DIM / 4; ++j) {
        float4 mv = muv[j];
        float4 sv = sgv[j];
        kl += mv.x * mv.x + sv.x - logf(sv.x) - 1.0f;
        kl += mv.y * mv.y + sv.y - logf(sv.y) - 1.0f;
        kl += mv.z * mv.z + sv.z - logf(sv.z) - 1.0f;
        kl += mv.w * mv.w + sv.w - logf(sv.w) - 1.0f;
    }
    kl *= 0.5f;

    // Wave-level reduction in double, then one atomic per wave per value.
    double dk = (double)kl;
    double dr = (double)rec;
#pragma unroll
    for (int off = 32; off > 0; off >>= 1) {
        dk += __shfl_down(dk, off);
        dr += __shfl_down(dr, off);
    }
    if ((threadIdx.x & 63) == 0) {
        atomicAdd(&ws_acc[0], dk);
        atomicAdd(&ws_acc[1], dr);
    }
}

__global__ void loss_finalize_kernel(const double* __restrict__ ws_acc,
                                     float* __restrict__ out)
{
    double kl  = ws_acc[0] / (double)N_TOT;
    double rec = ws_acc[1] / (double)N_TOT;
    out[0] = (float)(kl + rec);
    out[1] = (float)kl;
    out[2] = (float)rec;
}

extern "C" void kernel_launch(void* const* d_in, const int* in_sizes, int n_in,
                              void* d_out, int out_size, void* d_ws, size_t ws_size,
                              hipStream_t stream) {
    const float* y_true = (const float*)d_in[0];
    const float* y_pred = (const float*)d_in[1];
    const float* mu     = (const float*)d_in[2];
    const float* Sigma  = (const float*)d_in[3];
    float* out  = (float*)d_out;
    double* ws  = (double*)d_ws;

    // ws is re-poisoned to 0xAA before every launch -> zero the accumulators.
    hipMemsetAsync(ws, 0, 2 * sizeof(double), stream);

    loss_main_kernel<<<N_TOT / 256, 256, 0, stream>>>(y_true, y_pred, mu, Sigma, ws);
    loss_finalize_kernel<<<1, 1, 0, stream>>>(ws, out);
}

// Round 2
// 381.109 us; speedup vs baseline: 1.0003x; 1.0003x over previous
//
#include <hip/hip_runtime.h>
#include <math.h>

#define L_SAMP 128
#define N_TOT  65536
#define DIM    8
#define DZ_DIM 16
#define NTRI   36              // upper-triangular 8x8
#define NPB    64              // n's per block
#define CHUNKS 4               // L-axis split (one wave per chunk)
#define LPC    (L_SAMP / CHUNKS)   // 32 samples per thread
#define LDSTR  45              // 44 floats + 1 pad (45 coprime with 32 banks)

__host__ __device__ constexpr int tri(int d, int e) {   // d<=e, upper-tri index
    return d * DIM - d * (d - 1) / 2 + (e - d);
}
__host__ __device__ constexpr int gi(int i, int j) {    // i>=j, lower-tri index
    return i * (i + 1) / 2 + j;
}

// Block = 256 threads = 4 waves. Wave c handles L-chunk c for the block's 64 n's.
// Each thread accumulates s[8] + p[36] over its 32 samples; waves 1-3 dump
// partials to LDS; wave 0 combines, does packed 8x8 Cholesky (logdet + quad),
// adds the KL term, wave-reduces in double, one atomicAdd pair per block.
__global__ __launch_bounds__(256, 4) void loss_main_kernel(
    const float* __restrict__ y_true,
    const float* __restrict__ y_pred,
    const float* __restrict__ mu,
    const float* __restrict__ Sigma,
    double* __restrict__ ws_acc)
{
    __shared__ float lds[(CHUNKS - 1) * NPB * LDSTR];   // 34,560 B

    const int t = threadIdx.x;
    const int i = t & 63;            // local n
    const int c = t >> 6;            // L-chunk == wave id
    const int n = blockIdx.x * NPB + i;

    float s[DIM];
    float p[NTRI];
#pragma unroll
    for (int d = 0; d < DIM; ++d) s[d] = 0.0f;
#pragma unroll
    for (int j = 0; j < NTRI; ++j) p[j] = 0.0f;

    const float* src = y_pred + ((size_t)(c * LPC) * N_TOT + (size_t)n) * DIM;
    const size_t strideF = (size_t)N_TOT * DIM;   // floats per l-step (2 MiB)

#pragma unroll 2
    for (int l = 0; l < LPC; ++l) {
        const float4* q = reinterpret_cast<const float4*>(src + (size_t)l * strideF);
        float4 a = q[0];
        float4 b = q[1];
        float y[DIM] = {a.x, a.y, a.z, a.w, b.x, b.y, b.z, b.w};
#pragma unroll
        for (int d = 0; d < DIM; ++d) s[d] += y[d];
#pragma unroll
        for (int d = 0; d < DIM; ++d)
#pragma unroll
            for (int e = d; e < DIM; ++e)
                p[tri(d, e)] += y[d] * y[e];
    }

    // waves 1..3 publish partials
    if (c > 0) {
        float* dst = &lds[((c - 1) * NPB + i) * LDSTR];
#pragma unroll
        for (int d = 0; d < DIM; ++d) dst[d] = s[d];
#pragma unroll
        for (int j = 0; j < NTRI; ++j) dst[DIM + j] = p[j];
    }
    __syncthreads();

    if (c == 0) {
        // combine the 3 published partials
#pragma unroll
        for (int k = 0; k < CHUNKS - 1; ++k) {
            const float* srcl = &lds[(k * NPB + i) * LDSTR];
#pragma unroll
            for (int d = 0; d < DIM; ++d) s[d] += srcl[d];
#pragma unroll
            for (int j = 0; j < NTRI; ++j) p[j] += srcl[DIM + j];
        }

        float mean[DIM];
#pragma unroll
        for (int d = 0; d < DIM; ++d) mean[d] = s[d] * (1.0f / L_SAMP);

        // C (packed upper-tri) = (P - L*mean*mean^T) / (L-1), in place over p[]
#pragma unroll
        for (int d = 0; d < DIM; ++d)
#pragma unroll
            for (int e = d; e < DIM; ++e)
                p[tri(d, e)] = (p[tri(d, e)] - (float)L_SAMP * mean[d] * mean[e])
                               * (1.0f / (L_SAMP - 1));

        // m = mean - y_true[n]
        const float4* yt = reinterpret_cast<const float4*>(y_true + (size_t)n * DIM);
        float4 t0 = yt[0];
        float4 t1 = yt[1];
        float m[DIM] = {mean[0] - t0.x, mean[1] - t0.y, mean[2] - t0.z, mean[3] - t0.w,
                        mean[4] - t1.x, mean[5] - t1.y, mean[6] - t1.z, mean[7] - t1.w};

        // packed Cholesky: C = G G^T, logdet = sum log(diag residual)
        float G[NTRI];
        float logdet = 0.0f;
#pragma unroll
        for (int k = 0; k < DIM; ++k) {
            float diag = p[tri(k, k)];
#pragma unroll
            for (int j = 0; j < DIM; ++j)
                if (j < k) diag -= G[gi(k, j)] * G[gi(k, j)];
            float gkk = sqrtf(diag);
            G[gi(k, k)] = gkk;
            logdet += logf(diag);
            float inv = 1.0f / gkk;
#pragma unroll
            for (int r = 0; r < DIM; ++r) {
                if (r > k) {
                    float v = p[tri(k, r)];
#pragma unroll
                    for (int j = 0; j < DIM; ++j)
                        if (j < k) v -= G[gi(r, j)] * G[gi(k, j)];
                    G[gi(r, k)] = v * inv;
                }
            }
        }

        // forward solve G z = m; quad = ||z||^2
        float z[DIM];
        float quad = 0.0f;
#pragma unroll
        for (int r = 0; r < DIM; ++r) {
            float v = m[r];
#pragma unroll
            for (int j = 0; j < DIM; ++j)
                if (j < r) v -= G[gi(r, j)] * z[j];
            z[r] = v / G[gi(r, r)];
            quad += z[r] * z[r];
        }
        float rec = 0.5f * (logdet + quad);

        // KL: 0.5 * sum_j (mu^2 + Sigma - log Sigma - 1)
        const float4* muv = reinterpret_cast<const float4*>(mu + (size_t)n * DZ_DIM);
        const float4* sgv = reinterpret_cast<const float4*>(Sigma + (size_t)n * DZ_DIM);
        float kl = 0.0f;
#pragma unroll
        for (int j = 0; j < DZ_DIM / 4; ++j) {
            float4 mv = muv[j];
            float4 sv = sgv[j];
            kl += mv.x * mv.x + sv.x - logf(sv.x) - 1.0f;
            kl += mv.y * mv.y + sv.y - logf(sv.y) - 1.0f;
            kl += mv.z * mv.z + sv.z - logf(sv.z) - 1.0f;
            kl += mv.w * mv.w + sv.w - logf(sv.w) - 1.0f;
        }
        kl *= 0.5f;

        // wave-0 reduction in double, one atomic pair per block
        double dk = (double)kl;
        double dr = (double)rec;
#pragma unroll
        for (int off = 32; off > 0; off >>= 1) {
            dk += __shfl_down(dk, off);
            dr += __shfl_down(dr, off);
        }
        if (i == 0) {
            atomicAdd(&ws_acc[0], dk);
            atomicAdd(&ws_acc[1], dr);
        }
    }
}

__global__ void loss_finalize_kernel(const double* __restrict__ ws_acc,
                                     float* __restrict__ out)
{
    double kl  = ws_acc[0] / (double)N_TOT;
    double rec = ws_acc[1] / (double)N_TOT;
    out[0] = (float)(kl + rec);
    out[1] = (float)kl;
    out[2] = (float)rec;
}

extern "C" void kernel_launch(void* const* d_in, const int* in_sizes, int n_in,
                              void* d_out, int out_size, void* d_ws, size_t ws_size,
                              hipStream_t stream) {
    const float* y_true = (const float*)d_in[0];
    const float* y_pred = (const float*)d_in[1];
    const float* mu     = (const float*)d_in[2];
    const float* Sigma  = (const float*)d_in[3];
    float* out  = (float*)d_out;
    double* ws  = (double*)d_ws;

    // ws is re-poisoned to 0xAA before every launch -> zero the accumulators.
    hipMemsetAsync(ws, 0, 2 * sizeof(double), stream);

    loss_main_kernel<<<N_TOT / NPB, 256, 0, stream>>>(y_true, y_pred, mu, Sigma, ws);
    loss_finalize_kernel<<<1, 1, 0, stream>>>(ws, out);
}